// Round 5
// baseline (500.111 us; speedup 1.0000x reference)
//
#include <hip/hip_runtime.h>

typedef __attribute__((ext_vector_type(8))) short short8;
typedef __attribute__((ext_vector_type(4))) float floatx4;

#define B_ 2
#define S_ 2048
#define H_ 2048
#define LOG2E 1.44269504088896f

#define MFMA(a, b, c) __builtin_amdgcn_mfma_f32_16x16x32_bf16(a, b, c, 0, 0, 0)

__device__ __forceinline__ unsigned short f2bf(float f) {
    unsigned int x = __builtin_bit_cast(unsigned int, f);
    unsigned int r = x + 0x7FFFu + ((x >> 16) & 1u);
    return (unsigned short)(r >> 16);
}

__device__ __forceinline__ void gload_lds16(const unsigned short* g, unsigned short* l) {
    __builtin_amdgcn_global_load_lds(
        (const __attribute__((address_space(1))) void*)g,
        (__attribute__((address_space(3))) void*)l, 16, 0, 0);
}

// ---------------- elementwise f32 -> bf16 convert (vectorized) ---------------
__global__ __launch_bounds__(256) void conv_f2b(const float* __restrict__ in,
                                                unsigned short* __restrict__ out, int n4) {
    int i = blockIdx.x * 256 + threadIdx.x;
    if (i < n4) {
        float4 v = ((const float4*)in)[i];
        ushort4 o;
        o.x = f2bf(v.x); o.y = f2bf(v.y); o.z = f2bf(v.z); o.w = f2bf(v.w);
        ((ushort4*)out)[i] = o;
    }
}

// ---------------- tiled transpose+convert: f32 in[R][C] -> bf16 out[C][R] ----
__global__ __launch_bounds__(256) void tr_f2b(const float* __restrict__ in,
                                              unsigned short* __restrict__ out,
                                              int R, int C) {
    __shared__ unsigned short t[32][33];
    int c0 = blockIdx.x * 32, r0 = blockIdx.y * 32;
    int tx = threadIdx.x & 31, ty = threadIdx.x >> 5;  // 32 x 8
#pragma unroll
    for (int i = 0; i < 32; i += 8)
        t[ty + i][tx] = f2bf(in[(size_t)(r0 + ty + i) * C + c0 + tx]);
    __syncthreads();
#pragma unroll
    for (int i = 0; i < 32; i += 8)
        out[(size_t)(c0 + ty + i) * R + r0 + tx] = t[tx][ty + i];
}

// -------- fused Wq/Wk/Wv transpose+convert into WqkvT[3072][2048] ------------
__global__ __launch_bounds__(256) void tr_wqkv(const float* __restrict__ Wq,
                                               const float* __restrict__ Wk,
                                               const float* __restrict__ Wv,
                                               unsigned short* __restrict__ WqkvT) {
    __shared__ unsigned short t[32][33];
    int bx = blockIdx.x;  // 0..95
    const float* src; int C, c0, orow;
    if (bx < 64)      { src = Wq; C = 2048; c0 = bx * 32;        orow = bx * 32; }
    else if (bx < 80) { src = Wk; C = 512;  c0 = (bx - 64) * 32; orow = 2048 + (bx - 64) * 32; }
    else              { src = Wv; C = 512;  c0 = (bx - 80) * 32; orow = 2560 + (bx - 80) * 32; }
    int r0 = blockIdx.y * 32;
    int tx = threadIdx.x & 31, ty = threadIdx.x >> 5;
#pragma unroll
    for (int i = 0; i < 32; i += 8)
        t[ty + i][tx] = f2bf(src[(size_t)(r0 + ty + i) * C + c0 + tx]);
    __syncthreads();
#pragma unroll
    for (int i = 0; i < 32; i += 8)
        WqkvT[(size_t)(orow + ty + i) * 2048 + r0 + tx] = t[tx][ty + i];
}

// -------- bf16 tiled transpose with input pitch, batched on z ----------------
__global__ __launch_bounds__(256) void tr_bf16(const unsigned short* __restrict__ in,
                                               unsigned short* __restrict__ out,
                                               int R, int C, int ipitch,
                                               size_t ibs, size_t obs) {
    __shared__ unsigned short t[32][33];
    in += (size_t)blockIdx.z * ibs; out += (size_t)blockIdx.z * obs;
    int c0 = blockIdx.x * 32, r0 = blockIdx.y * 32;
    int tx = threadIdx.x & 31, ty = threadIdx.x >> 5;
#pragma unroll
    for (int i = 0; i < 32; i += 8)
        t[ty + i][tx] = in[(size_t)(r0 + ty + i) * ipitch + c0 + tx];
    __syncthreads();
#pragma unroll
    for (int i = 0; i < 32; i += 8)
        out[(size_t)(c0 + ty + i) * R + r0 + tx] = t[tx][ty + i];
}

// ---------------- GEMM: C[M][N] = A[M][K] x Bt[N][K]^T + bias ----------------
// bias from 3 arrays split at columns s1/s2 (pass s1=s2=1<<30 for single bias).
template <bool OUT_F32>
__global__ __launch_bounds__(256) void gemm_bt(const unsigned short* __restrict__ A,
                                               const unsigned short* __restrict__ Bt,
                                               const float* __restrict__ b0,
                                               const float* __restrict__ b1,
                                               const float* __restrict__ b2,
                                               int s1, int s2,
                                               void* __restrict__ Cv,
                                               int M, int N, int K) {
    __shared__ unsigned short As[128 * 64];
    __shared__ unsigned short Bs[128 * 64];
    const int t = threadIdx.x;
    const int lane = t & 63;
    const int wave = t >> 6;
    const int qlane = lane & 15;
    const int quad = lane >> 4;
    const int wm = (wave >> 1) * 64;
    const int wn = (wave & 1) * 64;
    const int bm = blockIdx.y * 128;
    const int bn = blockIdx.x * 128;
    const int srow = t >> 3;
    const int scc = (t & 7) * 8;
    const int gc8 = (((t & 7) ^ (2 * ((t >> 5) & 3))) * 8);
    const int rsw = 2 * (qlane >> 2);

    floatx4 acc[4][4] = {};

    for (int k0 = 0; k0 < K; k0 += 64) {
        __syncthreads();
#pragma unroll
        for (int r = 0; r < 4; ++r) {
            int row = r * 32 + srow;
            gload_lds16(A + (size_t)(bm + row) * K + k0 + gc8, &As[row * 64 + scc]);
        }
#pragma unroll
        for (int r = 0; r < 4; ++r) {
            int row = r * 32 + srow;
            gload_lds16(Bt + (size_t)(bn + row) * K + k0 + gc8, &Bs[row * 64 + scc]);
        }
        __syncthreads();
#pragma unroll
        for (int kk = 0; kk < 2; ++kk) {
            short8 a[4], b[4];
#pragma unroll
            for (int i = 0; i < 4; ++i)
                a[i] = *(const short8*)&As[(wm + i * 16 + qlane) * 64 + ((kk * 4 + quad) ^ rsw) * 8];
#pragma unroll
            for (int j = 0; j < 4; ++j)
                b[j] = *(const short8*)&Bs[(wn + j * 16 + qlane) * 64 + ((kk * 4 + quad) ^ rsw) * 8];
#pragma unroll
            for (int i = 0; i < 4; ++i)
#pragma unroll
                for (int j = 0; j < 4; ++j)
                    acc[i][j] = MFMA(a[i], b[j], acc[i][j]);
        }
    }
#pragma unroll
    for (int j = 0; j < 4; ++j) {
        int col = bn + wn + j * 16 + qlane;
        int cc = col; const float* bp = b0;
        if (col >= s2)      { bp = b2; cc = col - s2; }
        else if (col >= s1) { bp = b1; cc = col - s1; }
        float bvv = bp[cc];
#pragma unroll
        for (int i = 0; i < 4; ++i) {
            int row0 = bm + wm + i * 16 + quad * 4;
#pragma unroll
            for (int r = 0; r < 4; ++r) {
                float v = acc[i][j][r] + bvv;
                if (OUT_F32)
                    ((float*)Cv)[(size_t)(row0 + r) * N + col] = v;
                else
                    ((unsigned short*)Cv)[(size_t)(row0 + r) * N + col] = f2bf(v);
            }
        }
    }
}

// ---------------- Flash attention: barrier-free, 1-wave blocks ---------------
// 4096 blocks x 64 threads; each wave owns 32 q-rows of one head and loops all
// 32 key-tiles. K b-frags and V^T b-frags are 16B-contiguous in global memory
// (each key-row slice = one aligned 128B line), so no LDS staging and NO
// __syncthreads at all. Only LDS use: 4KB private Ps for the C->A layout
// round-trip (intra-wave, ordered by lgkmcnt). launch_bounds(64,4) caps VGPR
// at 128 -> 16 blocks/CU -> grid 4096 packs exactly, no dispatch tail.
// Block decode groups same-(b,kvh) jobs onto the same CU/XCD (round-robin
// dispatch heuristic; perf-only, correctness placement-independent).
__global__ __launch_bounds__(64, 4) void attn_kernel(const unsigned short* __restrict__ qkv,
                                                     const unsigned short* __restrict__ vtb,
                                                     const float* __restrict__ mask,
                                                     unsigned short* __restrict__ ob) {
    const int bid = blockIdx.x;          // 0..4095
    // bits[2:0]+8*bit[8] -> (b,kvh) pair; bits[7:3] + 32*bits[11:9] -> job idx
    const int pair = (bid & 7) | (((bid >> 8) & 1) << 3);   // 0..15
    const int b = pair >> 3;
    const int kvh = pair & 7;
    const int idx = ((bid >> 3) & 31) | (((bid >> 9) & 7) << 5);  // 0..255
    const int qsub = idx & 3;
    const int qt = idx >> 2;             // 0..63
    const int head = kvh * 4 + qsub;
    const int qcol = head * 64;
    const int kcol = 2048 + kvh * 64;    // K slice inside qkv row
    const int vch = kvh * 64;            // Vt channel base
    const int q0 = qt * 32;

    const int lane = threadIdx.x;        // 0..63
    const int qlane = lane & 15;
    const int quad = lane >> 4;

    __shared__ unsigned short Ps[32 * 64];

    const int rsw = 2 * (qlane >> 2);
    const float scale2 = 0.125f * LOG2E;

    const unsigned short* kbase = qkv + (size_t)b * S_ * 3072 + kcol;
    const unsigned short* vbase = vtb + (size_t)(b * 512 + vch) * S_;
    const float* mbase = mask + (size_t)b * S_;

    // Q a-frags straight from global (16B contiguous per lane)
    short8 aq[2][2];
#pragma unroll
    for (int mi = 0; mi < 2; ++mi)
#pragma unroll
        for (int kk = 0; kk < 2; ++kk)
            aq[mi][kk] = *(const short8*)(qkv +
                (size_t)(b * S_ + q0 + mi * 16 + qlane) * 3072 + qcol + kk * 32 + quad * 8);

    // ones B-fragment: B[k][0]=1 -> row-sum lands in column 0 of osum
    short8 ones;
    {
        short v = (qlane == 0) ? (short)0x3F80 : (short)0;
        ones = (short8){v, v, v, v, v, v, v, v};
    }

    floatx4 o[2][4] = {};
    floatx4 osum[2] = {};

    for (int kt = 0; kt < 32; ++kt) {
        // ---- QK^T: 32 q-rows x 64 keys; K b-frags from global ----
        floatx4 s[2][4] = {};
#pragma unroll
        for (int j = 0; j < 4; ++j) {
            const unsigned short* kr = kbase + (size_t)(kt * 64 + j * 16 + qlane) * 3072 + quad * 8;
            short8 bk0 = *(const short8*)kr;
            short8 bk1 = *(const short8*)(kr + 32);
#pragma unroll
            for (int mi = 0; mi < 2; ++mi) {
                s[mi][j] = MFMA(aq[mi][0], bk0, s[mi][j]);
                s[mi][j] = MFMA(aq[mi][1], bk1, s[mi][j]);
            }
        }

        float m2[4];
#pragma unroll
        for (int j = 0; j < 4; ++j)
            m2[j] = mbase[kt * 64 + j * 16 + qlane] * LOG2E;

        // ---- exp2 + P store (half-up round hi16, swizzled chunks) ----
#pragma unroll
        for (int mi = 0; mi < 2; ++mi)
#pragma unroll
            for (int j = 0; j < 4; ++j) {
                int ebase = (mi * 16 + quad * 4) * 64 + 16 * (j ^ quad) + qlane;
#pragma unroll
                for (int r = 0; r < 4; ++r) {
                    float p = __builtin_amdgcn_exp2f(s[mi][j][r] * scale2 + m2[j]);
                    unsigned int u = __builtin_bit_cast(unsigned int, p) + 0x8000u;
                    Ps[ebase + r * 64] = (unsigned short)(u >> 16);
                }
            }

        // ---- PV + row-sum: V^T b-frags from global; P a-frags from LDS ----
#pragma unroll
        for (int kk = 0; kk < 2; ++kk) {
            short8 ap[2];
#pragma unroll
            for (int mi = 0; mi < 2; ++mi)
                ap[mi] = *(const short8*)&Ps[(mi * 16 + qlane) * 64 + ((kk * 4 + quad) ^ rsw) * 8];
#pragma unroll
            for (int j2 = 0; j2 < 4; ++j2) {
                short8 bv = *(const short8*)(vbase + (size_t)(j2 * 16 + qlane) * S_ +
                                             kt * 64 + kk * 32 + quad * 8);
#pragma unroll
                for (int mi = 0; mi < 2; ++mi)
                    o[mi][j2] = MFMA(ap[mi], bv, o[mi][j2]);
            }
#pragma unroll
            for (int mi = 0; mi < 2; ++mi)
                osum[mi] = MFMA(ap[mi], ones, osum[mi]);
        }
    }

    // ---- epilogue: broadcast row-sum (col 0 of osum), normalize, store ----
#pragma unroll
    for (int mi = 0; mi < 2; ++mi)
#pragma unroll
        for (int r = 0; r < 4; ++r) {
            float sm = __shfl(osum[mi][r], quad * 16, 64);
            float inv = 1.0f / sm;
            int row = q0 + mi * 16 + quad * 4 + r;
#pragma unroll
            for (int j2 = 0; j2 < 4; ++j2)
                ob[(size_t)(b * S_ + row) * H_ + qcol + j2 * 16 + qlane] = f2bf(o[mi][j2][r] * inv);
        }
}

extern "C" void kernel_launch(void* const* d_in, const int* in_sizes, int n_in,
                              void* d_out, int out_size, void* d_ws, size_t ws_size,
                              hipStream_t stream) {
    const float* x    = (const float*)d_in[0];
    const float* mask = (const float*)d_in[1];
    const float* Wq   = (const float*)d_in[2];
    const float* bq   = (const float*)d_in[3];
    const float* Wk   = (const float*)d_in[4];
    const float* bk   = (const float*)d_in[5];
    const float* Wv   = (const float*)d_in[6];
    const float* bv   = (const float*)d_in[7];
    const float* Wo   = (const float*)d_in[8];
    const float* bo   = (const float*)d_in[9];
    float* out = (float*)d_out;

    // workspace (bf16 elems), 58.7 MB total:
    //   x_bf [4096][2048] (later: attn out), qkv [4096][3072],
    //   vt [2][512][2048], WqkvT [3072][2048] (later: WoT [2048][2048])
    unsigned short* ws = (unsigned short*)d_ws;
    unsigned short* x_bf   = ws;
    unsigned short* qkv    = x_bf + (size_t)4096 * 2048;
    unsigned short* vt_buf = qkv + (size_t)4096 * 3072;
    unsigned short* WqkvT  = vt_buf + (size_t)2 * 512 * 2048;
    unsigned short* WoT    = WqkvT;           // aliased: Wo transposed after QKV GEMM
    unsigned short* a_buf  = x_bf;            // aliased: x consumed by QKV GEMM

    const int BIG = 1 << 30;
    dim3 blk(256);
    // x -> bf16
    conv_f2b<<<dim3(4096 * 2048 / 4 / 256), blk, 0, stream>>>(x, x_bf, 4096 * 2048 / 4);
    // Wq|Wk|Wv -> WqkvT [3072][2048] (one launch)
    tr_wqkv<<<dim3(96, 64), blk, 0, stream>>>(Wq, Wk, Wv, WqkvT);
    // fused QKV projection: [4096][2048] x [3072][2048]^T -> qkv [4096][3072]
    gemm_bt<false><<<dim3(24, 32), blk, 0, stream>>>(x_bf, WqkvT, bq, bk, bv, 2048, 2560,
                                                     qkv, 4096, 3072, 2048);
    // Wo -> WoT (into WqkvT's space, now dead)
    tr_f2b<<<dim3(64, 64), blk, 0, stream>>>(Wo, WoT, 2048, 2048);
    // per-batch V transpose: qkv[b][s][2560..3071] -> vt [b][512][S]
    tr_bf16<<<dim3(16, 64, 2), blk, 0, stream>>>(qkv + 2560, vt_buf, 2048, 512, 3072,
                                                 (size_t)2048 * 3072, (size_t)512 * 2048);
    // attention (barrier-free 1-wave blocks; writes a_buf = x_bf)
    attn_kernel<<<dim3(4096), dim3(64), 0, stream>>>(qkv, vt_buf, mask, a_buf);
    // output projection (f32 out)
    gemm_bt<true><<<dim3(16, 32), blk, 0, stream>>>(a_buf, WoT, bo, bo, bo, BIG, BIG,
                                                    out, 4096, 2048, 2048);
}

// Round 6
// 402.247 us; speedup vs baseline: 1.2433x; 1.2433x over previous
//
#include <hip/hip_runtime.h>

typedef __attribute__((ext_vector_type(8))) short short8;
typedef __attribute__((ext_vector_type(4))) float floatx4;

#define B_ 2
#define S_ 2048
#define H_ 2048
#define LOG2E 1.44269504088896f

#define MFMA(a, b, c) __builtin_amdgcn_mfma_f32_16x16x32_bf16(a, b, c, 0, 0, 0)

__device__ __forceinline__ unsigned short f2bf(float f) {
    unsigned int x = __builtin_bit_cast(unsigned int, f);
    unsigned int r = x + 0x7FFFu + ((x >> 16) & 1u);
    return (unsigned short)(r >> 16);
}

__device__ __forceinline__ void gload_lds16(const unsigned short* g, unsigned short* l) {
    __builtin_amdgcn_global_load_lds(
        (const __attribute__((address_space(1))) void*)g,
        (__attribute__((address_space(3))) void*)l, 16, 0, 0);
}

// ---------------- elementwise f32 -> bf16 convert (vectorized) ---------------
__global__ __launch_bounds__(256) void conv_f2b(const float* __restrict__ in,
                                                unsigned short* __restrict__ out, int n4) {
    int i = blockIdx.x * 256 + threadIdx.x;
    if (i < n4) {
        float4 v = ((const float4*)in)[i];
        ushort4 o;
        o.x = f2bf(v.x); o.y = f2bf(v.y); o.z = f2bf(v.z); o.w = f2bf(v.w);
        ((ushort4*)out)[i] = o;
    }
}

// ---------------- tiled transpose+convert: f32 in[R][C] -> bf16 out[C][R] ----
__global__ __launch_bounds__(256) void tr_f2b(const float* __restrict__ in,
                                              unsigned short* __restrict__ out,
                                              int R, int C) {
    __shared__ unsigned short t[32][33];
    int c0 = blockIdx.x * 32, r0 = blockIdx.y * 32;
    int tx = threadIdx.x & 31, ty = threadIdx.x >> 5;  // 32 x 8
#pragma unroll
    for (int i = 0; i < 32; i += 8)
        t[ty + i][tx] = f2bf(in[(size_t)(r0 + ty + i) * C + c0 + tx]);
    __syncthreads();
#pragma unroll
    for (int i = 0; i < 32; i += 8)
        out[(size_t)(c0 + ty + i) * R + r0 + tx] = t[tx][ty + i];
}

// -------- fused Wq/Wk/Wv transpose+convert into WqkvT[3072][2048] ------------
__global__ __launch_bounds__(256) void tr_wqkv(const float* __restrict__ Wq,
                                               const float* __restrict__ Wk,
                                               const float* __restrict__ Wv,
                                               unsigned short* __restrict__ WqkvT) {
    __shared__ unsigned short t[32][33];
    int bx = blockIdx.x;  // 0..95
    const float* src; int C, c0, orow;
    if (bx < 64)      { src = Wq; C = 2048; c0 = bx * 32;        orow = bx * 32; }
    else if (bx < 80) { src = Wk; C = 512;  c0 = (bx - 64) * 32; orow = 2048 + (bx - 64) * 32; }
    else              { src = Wv; C = 512;  c0 = (bx - 80) * 32; orow = 2560 + (bx - 80) * 32; }
    int r0 = blockIdx.y * 32;
    int tx = threadIdx.x & 31, ty = threadIdx.x >> 5;
#pragma unroll
    for (int i = 0; i < 32; i += 8)
        t[ty + i][tx] = f2bf(src[(size_t)(r0 + ty + i) * C + c0 + tx]);
    __syncthreads();
#pragma unroll
    for (int i = 0; i < 32; i += 8)
        WqkvT[(size_t)(orow + ty + i) * 2048 + r0 + tx] = t[tx][ty + i];
}

// -------- bf16 tiled transpose with input pitch, batched on z ----------------
__global__ __launch_bounds__(256) void tr_bf16(const unsigned short* __restrict__ in,
                                               unsigned short* __restrict__ out,
                                               int R, int C, int ipitch,
                                               size_t ibs, size_t obs) {
    __shared__ unsigned short t[32][33];
    in += (size_t)blockIdx.z * ibs; out += (size_t)blockIdx.z * obs;
    int c0 = blockIdx.x * 32, r0 = blockIdx.y * 32;
    int tx = threadIdx.x & 31, ty = threadIdx.x >> 5;
#pragma unroll
    for (int i = 0; i < 32; i += 8)
        t[ty + i][tx] = in[(size_t)(r0 + ty + i) * ipitch + c0 + tx];
    __syncthreads();
#pragma unroll
    for (int i = 0; i < 32; i += 8)
        out[(size_t)(c0 + ty + i) * R + r0 + tx] = t[tx][ty + i];
}

// ---------------- GEMM: C[M][N] = A[M][K] x Bt[N][K]^T + bias ----------------
// bias from 3 arrays split at columns s1/s2 (pass s1=s2=1<<30 for single bias).
template <bool OUT_F32>
__global__ __launch_bounds__(256) void gemm_bt(const unsigned short* __restrict__ A,
                                               const unsigned short* __restrict__ Bt,
                                               const float* __restrict__ b0,
                                               const float* __restrict__ b1,
                                               const float* __restrict__ b2,
                                               int s1, int s2,
                                               void* __restrict__ Cv,
                                               int M, int N, int K) {
    __shared__ unsigned short As[128 * 64];
    __shared__ unsigned short Bs[128 * 64];
    const int t = threadIdx.x;
    const int lane = t & 63;
    const int wave = t >> 6;
    const int qlane = lane & 15;
    const int quad = lane >> 4;
    const int wm = (wave >> 1) * 64;
    const int wn = (wave & 1) * 64;
    const int bm = blockIdx.y * 128;
    const int bn = blockIdx.x * 128;
    const int srow = t >> 3;
    const int scc = (t & 7) * 8;
    const int gc8 = (((t & 7) ^ (2 * ((t >> 5) & 3))) * 8);
    const int rsw = 2 * (qlane >> 2);

    floatx4 acc[4][4] = {};

    for (int k0 = 0; k0 < K; k0 += 64) {
        __syncthreads();
#pragma unroll
        for (int r = 0; r < 4; ++r) {
            int row = r * 32 + srow;
            gload_lds16(A + (size_t)(bm + row) * K + k0 + gc8, &As[row * 64 + scc]);
        }
#pragma unroll
        for (int r = 0; r < 4; ++r) {
            int row = r * 32 + srow;
            gload_lds16(Bt + (size_t)(bn + row) * K + k0 + gc8, &Bs[row * 64 + scc]);
        }
        __syncthreads();
#pragma unroll
        for (int kk = 0; kk < 2; ++kk) {
            short8 a[4], b[4];
#pragma unroll
            for (int i = 0; i < 4; ++i)
                a[i] = *(const short8*)&As[(wm + i * 16 + qlane) * 64 + ((kk * 4 + quad) ^ rsw) * 8];
#pragma unroll
            for (int j = 0; j < 4; ++j)
                b[j] = *(const short8*)&Bs[(wn + j * 16 + qlane) * 64 + ((kk * 4 + quad) ^ rsw) * 8];
#pragma unroll
            for (int i = 0; i < 4; ++i)
#pragma unroll
                for (int j = 0; j < 4; ++j)
                    acc[i][j] = MFMA(a[i], b[j], acc[i][j]);
        }
    }
#pragma unroll
    for (int j = 0; j < 4; ++j) {
        int col = bn + wn + j * 16 + qlane;
        int cc = col; const float* bp = b0;
        if (col >= s2)      { bp = b2; cc = col - s2; }
        else if (col >= s1) { bp = b1; cc = col - s1; }
        float bvv = bp[cc];
#pragma unroll
        for (int i = 0; i < 4; ++i) {
            int row0 = bm + wm + i * 16 + quad * 4;
#pragma unroll
            for (int r = 0; r < 4; ++r) {
                float v = acc[i][j][r] + bvv;
                if (OUT_F32)
                    ((float*)Cv)[(size_t)(row0 + r) * N + col] = v;
                else
                    ((unsigned short*)Cv)[(size_t)(row0 + r) * N + col] = f2bf(v);
            }
        }
    }
}

// ---------------- Flash attention (128-row Q tiles, 32 rows/wave) ------------
// grid (16 qtiles, 32 heads, 2 batch) = 1024 blocks, 256 threads.
// K double-buffered in LDS (16KB); V^T b-frags read DIRECTLY from global
// (16B-contiguous; verified R5); Ps 16KB -> LDS total 32KB. launch_bounds
// (256,4) -> 4 blocks/CU -> all 1024 blocks co-resident, zero dispatch tail.
// Row-sum via MFMA ones-column. One barrier per kt (protects Ks dbuf only).
__global__ __launch_bounds__(256, 4) void attn_kernel(const unsigned short* __restrict__ qkv,
                                                      const unsigned short* __restrict__ vtb,
                                                      const float* __restrict__ mask,
                                                      unsigned short* __restrict__ ob) {
    const int qt = blockIdx.x;
    const int head = blockIdx.y;
    const int b = blockIdx.z;
    const int kvh = head >> 2;
    const int qcol = head * 64;
    const int kcol = 2048 + kvh * 64;   // K slice inside qkv row
    const int vch = kvh * 64;           // Vt channel base
    const int q0 = qt * 128;
    const int t = threadIdx.x;
    const int lane = t & 63;
    const int wave = t >> 6;
    const int qlane = lane & 15;
    const int quad = lane >> 4;
    const int wr = wave * 32;

    __shared__ unsigned short Ks[2][64 * 64];
    __shared__ unsigned short Ps[128 * 64];

    const int gc8 = (((t & 7) ^ (2 * ((t >> 5) & 3))) * 8);  // swizzled global chunk
    const int rsw = 2 * (qlane >> 2);                        // read-side swizzle
    const float scale2 = 0.125f * LOG2E;

    const unsigned short* vbase = vtb + (size_t)(b * 512 + vch) * S_;

    // Q fragments straight from global (16B contiguous per lane)
    short8 aq[2][2];
#pragma unroll
    for (int mi = 0; mi < 2; ++mi)
#pragma unroll
        for (int kk = 0; kk < 2; ++kk)
            aq[mi][kk] = *(const short8*)(qkv +
                (size_t)(b * S_ + q0 + wr + mi * 16 + qlane) * 3072 + qcol + kk * 32 + quad * 8);

    // stage K tile 0 into buf 0
    {
        int row = t >> 3;
#pragma unroll
        for (int i = 0; i < 2; ++i) {
            int rr = row + 32 * i;
            gload_lds16(qkv + (size_t)(b * S_ + rr) * 3072 + kcol + gc8,
                        &Ks[0][(rr * 8 + (t & 7)) * 8]);
        }
    }

    // ones B-fragment: B[k][0]=1 -> row-sum lands in column 0 of osum
    short8 ones;
    {
        short v = (qlane == 0) ? (short)0x3F80 : (short)0;
        ones = (short8){v, v, v, v, v, v, v, v};
    }

    floatx4 o[2][4] = {};
    floatx4 osum[2] = {};

    __syncthreads();

    for (int kt = 0; kt < 32; ++kt) {
        const int cur = kt & 1;
        if (kt < 31) {
            const int nxt = cur ^ 1;
            int kn = (kt + 1) * 64;
            int row = t >> 3;
#pragma unroll
            for (int i = 0; i < 2; ++i) {
                int rr = row + 32 * i;
                gload_lds16(qkv + (size_t)(b * S_ + kn + rr) * 3072 + kcol + gc8,
                            &Ks[nxt][(rr * 8 + (t & 7)) * 8]);
            }
        }
        float m2[4];
#pragma unroll
        for (int j = 0; j < 4; ++j)
            m2[j] = mask[(size_t)b * S_ + kt * 64 + j * 16 + qlane] * LOG2E;

        // ---- QK^T: 32 q-rows x 64 keys per wave ----
        floatx4 s[2][4] = {};
#pragma unroll
        for (int j = 0; j < 4; ++j) {
            short8 bk0 = *(const short8*)&Ks[cur][(j * 16 + qlane) * 64 + ((0 + quad) ^ rsw) * 8];
            short8 bk1 = *(const short8*)&Ks[cur][(j * 16 + qlane) * 64 + ((4 + quad) ^ rsw) * 8];
#pragma unroll
            for (int mi = 0; mi < 2; ++mi) {
                s[mi][j] = MFMA(aq[mi][0], bk0, s[mi][j]);
                s[mi][j] = MFMA(aq[mi][1], bk1, s[mi][j]);
            }
        }

        // ---- exp2 + P store (half-up round, high-half b16 store, swizzled) ----
#pragma unroll
        for (int mi = 0; mi < 2; ++mi)
#pragma unroll
            for (int j = 0; j < 4; ++j) {
                int ebase = (wr + mi * 16 + quad * 4) * 64 + 16 * (j ^ quad) + qlane;
#pragma unroll
                for (int r = 0; r < 4; ++r) {
                    float p = __builtin_amdgcn_exp2f(s[mi][j][r] * scale2 + m2[j]);
                    unsigned int u = __builtin_bit_cast(unsigned int, p) + 0x8000u;
                    Ps[ebase + r * 64] = (unsigned short)(u >> 16);
                }
            }

        // ---- PV + row-sum: V^T b-frags from global; P a-frags from LDS ----
#pragma unroll
        for (int kk = 0; kk < 2; ++kk) {
            short8 ap[2];
#pragma unroll
            for (int mi = 0; mi < 2; ++mi)
                ap[mi] = *(const short8*)&Ps[(wr + mi * 16 + qlane) * 64 + ((kk * 4 + quad) ^ rsw) * 8];
#pragma unroll
            for (int j2 = 0; j2 < 4; ++j2) {
                short8 bv = *(const short8*)(vbase + (size_t)(j2 * 16 + qlane) * S_ +
                                             kt * 64 + kk * 32 + quad * 8);
#pragma unroll
                for (int mi = 0; mi < 2; ++mi)
                    o[mi][j2] = MFMA(ap[mi], bv, o[mi][j2]);
            }
#pragma unroll
            for (int mi = 0; mi < 2; ++mi)
                osum[mi] = MFMA(ap[mi], ones, osum[mi]);
        }

        __syncthreads();  // drains K prefetch + protects Ks buffer reuse
    }

    // ---- epilogue: broadcast row-sum (col 0 of osum), normalize, store ----
#pragma unroll
    for (int mi = 0; mi < 2; ++mi)
#pragma unroll
        for (int r = 0; r < 4; ++r) {
            float sm = __shfl(osum[mi][r], quad * 16, 64);
            float inv = 1.0f / sm;
            int row = q0 + wr + mi * 16 + quad * 4 + r;
#pragma unroll
            for (int j2 = 0; j2 < 4; ++j2)
                ob[(size_t)(b * S_ + row) * H_ + qcol + j2 * 16 + qlane] = f2bf(o[mi][j2][r] * inv);
        }
}

extern "C" void kernel_launch(void* const* d_in, const int* in_sizes, int n_in,
                              void* d_out, int out_size, void* d_ws, size_t ws_size,
                              hipStream_t stream) {
    const float* x    = (const float*)d_in[0];
    const float* mask = (const float*)d_in[1];
    const float* Wq   = (const float*)d_in[2];
    const float* bq   = (const float*)d_in[3];
    const float* Wk   = (const float*)d_in[4];
    const float* bk   = (const float*)d_in[5];
    const float* Wv   = (const float*)d_in[6];
    const float* bv   = (const float*)d_in[7];
    const float* Wo   = (const float*)d_in[8];
    const float* bo   = (const float*)d_in[9];
    float* out = (float*)d_out;

    // workspace (bf16 elems), 58.7 MB total:
    //   x_bf [4096][2048] (later: attn out), qkv [4096][3072],
    //   vt [2][512][2048], WqkvT [3072][2048] (later: WoT [2048][2048])
    unsigned short* ws = (unsigned short*)d_ws;
    unsigned short* x_bf   = ws;
    unsigned short* qkv    = x_bf + (size_t)4096 * 2048;
    unsigned short* vt_buf = qkv + (size_t)4096 * 3072;
    unsigned short* WqkvT  = vt_buf + (size_t)2 * 512 * 2048;
    unsigned short* WoT    = WqkvT;           // aliased: Wo transposed after QKV GEMM
    unsigned short* a_buf  = x_bf;            // aliased: x consumed by QKV GEMM

    const int BIG = 1 << 30;
    dim3 blk(256);
    // x -> bf16
    conv_f2b<<<dim3(4096 * 2048 / 4 / 256), blk, 0, stream>>>(x, x_bf, 4096 * 2048 / 4);
    // Wq|Wk|Wv -> WqkvT [3072][2048] (one launch)
    tr_wqkv<<<dim3(96, 64), blk, 0, stream>>>(Wq, Wk, Wv, WqkvT);
    // fused QKV projection: [4096][2048] x [3072][2048]^T -> qkv [4096][3072]
    gemm_bt<false><<<dim3(24, 32), blk, 0, stream>>>(x_bf, WqkvT, bq, bk, bv, 2048, 2560,
                                                     qkv, 4096, 3072, 2048);
    // Wo -> WoT (into WqkvT's space, now dead)
    tr_f2b<<<dim3(64, 64), blk, 0, stream>>>(Wo, WoT, 2048, 2048);
    // per-batch V transpose: qkv[b][s][2560..3071] -> vt [b][512][S]
    tr_bf16<<<dim3(16, 64, 2), blk, 0, stream>>>(qkv + 2560, vt_buf, 2048, 512, 3072,
                                                 (size_t)2048 * 3072, (size_t)512 * 2048);
    // attention (writes a_buf = x_bf)
    attn_kernel<<<dim3(16, 32, 2), blk, 0, stream>>>(qkv, vt_buf, mask, a_buf);
    // output projection (f32 out)
    gemm_bt<true><<<dim3(16, 32), blk, 0, stream>>>(a_buf, WoT, bo, bo, bo, BIG, BIG,
                                                    out, 4096, 2048, 2048);
}

// Round 7
// 401.995 us; speedup vs baseline: 1.2441x; 1.0006x over previous
//
#include <hip/hip_runtime.h>

typedef __attribute__((ext_vector_type(8))) short short8;
typedef __attribute__((ext_vector_type(4))) float floatx4;

#define B_ 2
#define S_ 2048
#define H_ 2048
#define LOG2E 1.44269504088896f

#define MFMA(a, b, c) __builtin_amdgcn_mfma_f32_16x16x32_bf16(a, b, c, 0, 0, 0)

__device__ __forceinline__ unsigned short f2bf(float f) {
    unsigned int x = __builtin_bit_cast(unsigned int, f);
    unsigned int r = x + 0x7FFFu + ((x >> 16) & 1u);
    return (unsigned short)(r >> 16);
}

__device__ __forceinline__ void gload_lds16(const unsigned short* g, unsigned short* l) {
    __builtin_amdgcn_global_load_lds(
        (const __attribute__((address_space(1))) void*)g,
        (__attribute__((address_space(3))) void*)l, 16, 0, 0);
}

// ---------------- elementwise f32 -> bf16 convert (vectorized) ---------------
__global__ __launch_bounds__(256) void conv_f2b(const float* __restrict__ in,
                                                unsigned short* __restrict__ out, int n4) {
    int i = blockIdx.x * 256 + threadIdx.x;
    if (i < n4) {
        float4 v = ((const float4*)in)[i];
        ushort4 o;
        o.x = f2bf(v.x); o.y = f2bf(v.y); o.z = f2bf(v.z); o.w = f2bf(v.w);
        ((ushort4*)out)[i] = o;
    }
}

// ---------------- tiled transpose+convert: f32 in[R][C] -> bf16 out[C][R] ----
__global__ __launch_bounds__(256) void tr_f2b(const float* __restrict__ in,
                                              unsigned short* __restrict__ out,
                                              int R, int C) {
    __shared__ unsigned short t[32][33];
    int c0 = blockIdx.x * 32, r0 = blockIdx.y * 32;
    int tx = threadIdx.x & 31, ty = threadIdx.x >> 5;  // 32 x 8
#pragma unroll
    for (int i = 0; i < 32; i += 8)
        t[ty + i][tx] = f2bf(in[(size_t)(r0 + ty + i) * C + c0 + tx]);
    __syncthreads();
#pragma unroll
    for (int i = 0; i < 32; i += 8)
        out[(size_t)(c0 + ty + i) * R + r0 + tx] = t[tx][ty + i];
}

// -------- fused Wq/Wk/Wv transpose+convert into WqkvT[3072][2048] ------------
__global__ __launch_bounds__(256) void tr_wqkv(const float* __restrict__ Wq,
                                               const float* __restrict__ Wk,
                                               const float* __restrict__ Wv,
                                               unsigned short* __restrict__ WqkvT) {
    __shared__ unsigned short t[32][33];
    int bx = blockIdx.x;  // 0..95
    const float* src; int C, c0, orow;
    if (bx < 64)      { src = Wq; C = 2048; c0 = bx * 32;        orow = bx * 32; }
    else if (bx < 80) { src = Wk; C = 512;  c0 = (bx - 64) * 32; orow = 2048 + (bx - 64) * 32; }
    else              { src = Wv; C = 512;  c0 = (bx - 80) * 32; orow = 2560 + (bx - 80) * 32; }
    int r0 = blockIdx.y * 32;
    int tx = threadIdx.x & 31, ty = threadIdx.x >> 5;
#pragma unroll
    for (int i = 0; i < 32; i += 8)
        t[ty + i][tx] = f2bf(src[(size_t)(r0 + ty + i) * C + c0 + tx]);
    __syncthreads();
#pragma unroll
    for (int i = 0; i < 32; i += 8)
        WqkvT[(size_t)(orow + ty + i) * 2048 + r0 + tx] = t[tx][ty + i];
}

// -------- bf16 tiled transpose with input pitch, batched on z ----------------
__global__ __launch_bounds__(256) void tr_bf16(const unsigned short* __restrict__ in,
                                               unsigned short* __restrict__ out,
                                               int R, int C, int ipitch,
                                               size_t ibs, size_t obs) {
    __shared__ unsigned short t[32][33];
    in += (size_t)blockIdx.z * ibs; out += (size_t)blockIdx.z * obs;
    int c0 = blockIdx.x * 32, r0 = blockIdx.y * 32;
    int tx = threadIdx.x & 31, ty = threadIdx.x >> 5;
#pragma unroll
    for (int i = 0; i < 32; i += 8)
        t[ty + i][tx] = in[(size_t)(r0 + ty + i) * ipitch + c0 + tx];
    __syncthreads();
#pragma unroll
    for (int i = 0; i < 32; i += 8)
        out[(size_t)(c0 + ty + i) * R + r0 + tx] = t[tx][ty + i];
}

// ---------------- GEMM: C[M][N] = A[M][K] x Bt[N][K]^T + bias ----------------
// bias from 3 arrays split at columns s1/s2 (pass s1=s2=1<<30 for single bias).
template <bool OUT_F32>
__global__ __launch_bounds__(256) void gemm_bt(const unsigned short* __restrict__ A,
                                               const unsigned short* __restrict__ Bt,
                                               const float* __restrict__ b0,
                                               const float* __restrict__ b1,
                                               const float* __restrict__ b2,
                                               int s1, int s2,
                                               void* __restrict__ Cv,
                                               int M, int N, int K) {
    __shared__ unsigned short As[128 * 64];
    __shared__ unsigned short Bs[128 * 64];
    const int t = threadIdx.x;
    const int lane = t & 63;
    const int wave = t >> 6;
    const int qlane = lane & 15;
    const int quad = lane >> 4;
    const int wm = (wave >> 1) * 64;
    const int wn = (wave & 1) * 64;
    const int bm = blockIdx.y * 128;
    const int bn = blockIdx.x * 128;
    const int srow = t >> 3;
    const int scc = (t & 7) * 8;
    const int gc8 = (((t & 7) ^ (2 * ((t >> 5) & 3))) * 8);
    const int rsw = 2 * (qlane >> 2);

    floatx4 acc[4][4] = {};

    for (int k0 = 0; k0 < K; k0 += 64) {
        __syncthreads();
#pragma unroll
        for (int r = 0; r < 4; ++r) {
            int row = r * 32 + srow;
            gload_lds16(A + (size_t)(bm + row) * K + k0 + gc8, &As[row * 64 + scc]);
        }
#pragma unroll
        for (int r = 0; r < 4; ++r) {
            int row = r * 32 + srow;
            gload_lds16(Bt + (size_t)(bn + row) * K + k0 + gc8, &Bs[row * 64 + scc]);
        }
        __syncthreads();
#pragma unroll
        for (int kk = 0; kk < 2; ++kk) {
            short8 a[4], b[4];
#pragma unroll
            for (int i = 0; i < 4; ++i)
                a[i] = *(const short8*)&As[(wm + i * 16 + qlane) * 64 + ((kk * 4 + quad) ^ rsw) * 8];
#pragma unroll
            for (int j = 0; j < 4; ++j)
                b[j] = *(const short8*)&Bs[(wn + j * 16 + qlane) * 64 + ((kk * 4 + quad) ^ rsw) * 8];
#pragma unroll
            for (int i = 0; i < 4; ++i)
#pragma unroll
                for (int j = 0; j < 4; ++j)
                    acc[i][j] = MFMA(a[i], b[j], acc[i][j]);
        }
    }
#pragma unroll
    for (int j = 0; j < 4; ++j) {
        int col = bn + wn + j * 16 + qlane;
        int cc = col; const float* bp = b0;
        if (col >= s2)      { bp = b2; cc = col - s2; }
        else if (col >= s1) { bp = b1; cc = col - s1; }
        float bvv = bp[cc];
#pragma unroll
        for (int i = 0; i < 4; ++i) {
            int row0 = bm + wm + i * 16 + quad * 4;
#pragma unroll
            for (int r = 0; r < 4; ++r) {
                float v = acc[i][j][r] + bvv;
                if (OUT_F32)
                    ((float*)Cv)[(size_t)(row0 + r) * N + col] = v;
                else
                    ((unsigned short*)Cv)[(size_t)(row0 + r) * N + col] = f2bf(v);
            }
        }
    }
}

// ---------------- Flash attention (128-row Q tiles, 32 rows/wave) ------------
// grid (16 qtiles, 32 heads, 2 batch) = 1024 blocks, 256 threads, 4 blocks/CU.
// K double-buffered in LDS via global_load_lds; V^T b-frags loaded into
// REGISTERS at the TOP of each iteration, ISSUED BEFORE the K prefetch so the
// s_waitcnt before PV is vmcnt(8) (K prefetch stays in flight — vmcnt is a
// FIFO; R6 issued V after K and waiting on V drained the K queue). QK+exp
// (~500cy) covers the V L2 latency. One barrier per kt, cheap drain.
__global__ __launch_bounds__(256, 4) void attn_kernel(const unsigned short* __restrict__ qkv,
                                                      const unsigned short* __restrict__ vtb,
                                                      const float* __restrict__ mask,
                                                      unsigned short* __restrict__ ob) {
    const int qt = blockIdx.x;
    const int head = blockIdx.y;
    const int b = blockIdx.z;
    const int kvh = head >> 2;
    const int qcol = head * 64;
    const int kcol = 2048 + kvh * 64;   // K slice inside qkv row
    const int vch = kvh * 64;           // Vt channel base
    const int q0 = qt * 128;
    const int t = threadIdx.x;
    const int lane = t & 63;
    const int wave = t >> 6;
    const int qlane = lane & 15;
    const int quad = lane >> 4;
    const int wr = wave * 32;

    __shared__ unsigned short Ks[2][64 * 64];
    __shared__ unsigned short Ps[128 * 64];

    const int gc8 = (((t & 7) ^ (2 * ((t >> 5) & 3))) * 8);  // swizzled global chunk
    const int rsw = 2 * (qlane >> 2);                        // read-side swizzle
    const float scale2 = 0.125f * LOG2E;

    const unsigned short* vbase = vtb + (size_t)(b * 512 + vch) * S_;
    const float* mbase = mask + (size_t)b * S_;

    // Q fragments straight from global (16B contiguous per lane)
    short8 aq[2][2];
#pragma unroll
    for (int mi = 0; mi < 2; ++mi)
#pragma unroll
        for (int kk = 0; kk < 2; ++kk)
            aq[mi][kk] = *(const short8*)(qkv +
                (size_t)(b * S_ + q0 + wr + mi * 16 + qlane) * 3072 + qcol + kk * 32 + quad * 8);

    // stage K tile 0 into buf 0
    {
        int row = t >> 3;
#pragma unroll
        for (int i = 0; i < 2; ++i) {
            int rr = row + 32 * i;
            gload_lds16(qkv + (size_t)(b * S_ + rr) * 3072 + kcol + gc8,
                        &Ks[0][(rr * 8 + (t & 7)) * 8]);
        }
    }

    // ones B-fragment: B[k][0]=1 -> row-sum lands in column 0 of osum
    short8 ones;
    {
        short v = (qlane == 0) ? (short)0x3F80 : (short)0;
        ones = (short8){v, v, v, v, v, v, v, v};
    }

    floatx4 o[2][4] = {};
    floatx4 osum[2] = {};

    __syncthreads();

    for (int kt = 0; kt < 32; ++kt) {
        const int cur = kt & 1;

        // ---- (1) V b-frags for THIS kt into registers — issued FIRST ----
        short8 vb[2][4];
#pragma unroll
        for (int kk = 0; kk < 2; ++kk)
#pragma unroll
            for (int j2 = 0; j2 < 4; ++j2)
                vb[kk][j2] = *(const short8*)(vbase + (size_t)(j2 * 16 + qlane) * S_ +
                                              kt * 64 + kk * 32 + quad * 8);
        // ---- (2) mask values for this kt ----
        float m2[4];
#pragma unroll
        for (int j = 0; j < 4; ++j)
            m2[j] = mbase[kt * 64 + j * 16 + qlane] * LOG2E;

        // ---- (3) K prefetch for kt+1 (async, stays in flight past PV) ----
        if (kt < 31) {
            const int nxt = cur ^ 1;
            int kn = (kt + 1) * 64;
            int row = t >> 3;
#pragma unroll
            for (int i = 0; i < 2; ++i) {
                int rr = row + 32 * i;
                gload_lds16(qkv + (size_t)(b * S_ + kn + rr) * 3072 + kcol + gc8,
                            &Ks[nxt][(rr * 8 + (t & 7)) * 8]);
            }
        }

        // ---- (4) QK^T: 32 q-rows x 64 keys per wave ----
        floatx4 s[2][4] = {};
#pragma unroll
        for (int j = 0; j < 4; ++j) {
            short8 bk0 = *(const short8*)&Ks[cur][(j * 16 + qlane) * 64 + ((0 + quad) ^ rsw) * 8];
            short8 bk1 = *(const short8*)&Ks[cur][(j * 16 + qlane) * 64 + ((4 + quad) ^ rsw) * 8];
#pragma unroll
            for (int mi = 0; mi < 2; ++mi) {
                s[mi][j] = MFMA(aq[mi][0], bk0, s[mi][j]);
                s[mi][j] = MFMA(aq[mi][1], bk1, s[mi][j]);
            }
        }

        // ---- (5) exp2 + P store (half-up round, hi16 store, swizzled) ----
#pragma unroll
        for (int mi = 0; mi < 2; ++mi)
#pragma unroll
            for (int j = 0; j < 4; ++j) {
                int ebase = (wr + mi * 16 + quad * 4) * 64 + 16 * (j ^ quad) + qlane;
#pragma unroll
                for (int r = 0; r < 4; ++r) {
                    float p = __builtin_amdgcn_exp2f(s[mi][j][r] * scale2 + m2[j]);
                    unsigned int u = __builtin_bit_cast(unsigned int, p) + 0x8000u;
                    Ps[ebase + r * 64] = (unsigned short)(u >> 16);
                }
            }

        // ---- (6) PV + row-sum: V from registers; P a-frags from LDS ----
#pragma unroll
        for (int kk = 0; kk < 2; ++kk) {
            short8 ap[2];
#pragma unroll
            for (int mi = 0; mi < 2; ++mi)
                ap[mi] = *(const short8*)&Ps[(wr + mi * 16 + qlane) * 64 + ((kk * 4 + quad) ^ rsw) * 8];
#pragma unroll
            for (int j2 = 0; j2 < 4; ++j2)
#pragma unroll
                for (int mi = 0; mi < 2; ++mi)
                    o[mi][j2] = MFMA(ap[mi], vb[kk][j2], o[mi][j2]);
#pragma unroll
            for (int mi = 0; mi < 2; ++mi)
                osum[mi] = MFMA(ap[mi], ones, osum[mi]);
        }

        __syncthreads();  // Ks dbuf protection; K prefetch has had full iter to land
    }

    // ---- epilogue: broadcast row-sum (col 0 of osum), normalize, store ----
#pragma unroll
    for (int mi = 0; mi < 2; ++mi)
#pragma unroll
        for (int r = 0; r < 4; ++r) {
            float sm = __shfl(osum[mi][r], quad * 16, 64);
            float inv = 1.0f / sm;
            int row = q0 + wr + mi * 16 + quad * 4 + r;
#pragma unroll
            for (int j2 = 0; j2 < 4; ++j2)
                ob[(size_t)(b * S_ + row) * H_ + qcol + j2 * 16 + qlane] = f2bf(o[mi][j2][r] * inv);
        }
}

extern "C" void kernel_launch(void* const* d_in, const int* in_sizes, int n_in,
                              void* d_out, int out_size, void* d_ws, size_t ws_size,
                              hipStream_t stream) {
    const float* x    = (const float*)d_in[0];
    const float* mask = (const float*)d_in[1];
    const float* Wq   = (const float*)d_in[2];
    const float* bq   = (const float*)d_in[3];
    const float* Wk   = (const float*)d_in[4];
    const float* bk   = (const float*)d_in[5];
    const float* Wv   = (const float*)d_in[6];
    const float* bv   = (const float*)d_in[7];
    const float* Wo   = (const float*)d_in[8];
    const float* bo   = (const float*)d_in[9];
    float* out = (float*)d_out;

    // workspace (bf16 elems), 58.7 MB total:
    //   x_bf [4096][2048] (later: attn out), qkv [4096][3072],
    //   vt [2][512][2048], WqkvT [3072][2048] (later: WoT [2048][2048])
    unsigned short* ws = (unsigned short*)d_ws;
    unsigned short* x_bf   = ws;
    unsigned short* qkv    = x_bf + (size_t)4096 * 2048;
    unsigned short* vt_buf = qkv + (size_t)4096 * 3072;
    unsigned short* WqkvT  = vt_buf + (size_t)2 * 512 * 2048;
    unsigned short* WoT    = WqkvT;           // aliased: Wo transposed after QKV GEMM
    unsigned short* a_buf  = x_bf;            // aliased: x consumed by QKV GEMM

    const int BIG = 1 << 30;
    dim3 blk(256);
    // x -> bf16
    conv_f2b<<<dim3(4096 * 2048 / 4 / 256), blk, 0, stream>>>(x, x_bf, 4096 * 2048 / 4);
    // Wq|Wk|Wv -> WqkvT [3072][2048] (one launch)
    tr_wqkv<<<dim3(96, 64), blk, 0, stream>>>(Wq, Wk, Wv, WqkvT);
    // fused QKV projection: [4096][2048] x [3072][2048]^T -> qkv [4096][3072]
    gemm_bt<false><<<dim3(24, 32), blk, 0, stream>>>(x_bf, WqkvT, bq, bk, bv, 2048, 2560,
                                                     qkv, 4096, 3072, 2048);
    // Wo -> WoT (into WqkvT's space, now dead)
    tr_f2b<<<dim3(64, 64), blk, 0, stream>>>(Wo, WoT, 2048, 2048);
    // per-batch V transpose: qkv[b][s][2560..3071] -> vt [b][512][S]
    tr_bf16<<<dim3(16, 64, 2), blk, 0, stream>>>(qkv + 2560, vt_buf, 2048, 512, 3072,
                                                 (size_t)2048 * 3072, (size_t)512 * 2048);
    // attention (writes a_buf = x_bf)
    attn_kernel<<<dim3(16, 32, 2), blk, 0, stream>>>(qkv, vt_buf, mask, a_buf);
    // output projection (f32 out)
    gemm_bt<true><<<dim3(16, 32), blk, 0, stream>>>(a_buf, WoT, bo, bo, bo, BIG, BIG,
                                                    out, 4096, 2048, 2048);
}

// Round 9
// 355.881 us; speedup vs baseline: 1.4053x; 1.1296x over previous
//
#include <hip/hip_runtime.h>

typedef __attribute__((ext_vector_type(8))) short short8;
typedef __attribute__((ext_vector_type(4))) float floatx4;

#define B_ 2
#define S_ 2048
#define H_ 2048
#define LOG2E 1.44269504088896f

#define MFMA(a, b, c) __builtin_amdgcn_mfma_f32_16x16x32_bf16(a, b, c, 0, 0, 0)

__device__ __forceinline__ unsigned short f2bf(float f) {
    unsigned int x = __builtin_bit_cast(unsigned int, f);
    unsigned int r = x + 0x7FFFu + ((x >> 16) & 1u);
    return (unsigned short)(r >> 16);
}

__device__ __forceinline__ void gload_lds16(const unsigned short* g, unsigned short* l) {
    __builtin_amdgcn_global_load_lds(
        (const __attribute__((address_space(1))) void*)g,
        (__attribute__((address_space(3))) void*)l, 16, 0, 0);
}

// ---------------- elementwise f32 -> bf16 convert (vectorized) ---------------
__global__ __launch_bounds__(256) void conv_f2b(const float* __restrict__ in,
                                                unsigned short* __restrict__ out, int n4) {
    int i = blockIdx.x * 256 + threadIdx.x;
    if (i < n4) {
        float4 v = ((const float4*)in)[i];
        ushort4 o;
        o.x = f2bf(v.x); o.y = f2bf(v.y); o.z = f2bf(v.z); o.w = f2bf(v.w);
        ((ushort4*)out)[i] = o;
    }
}

// ---------------- tiled transpose+convert: f32 in[R][C] -> bf16 out[C][R] ----
__global__ __launch_bounds__(256) void tr_f2b(const float* __restrict__ in,
                                              unsigned short* __restrict__ out,
                                              int R, int C) {
    __shared__ unsigned short t[32][33];
    int c0 = blockIdx.x * 32, r0 = blockIdx.y * 32;
    int tx = threadIdx.x & 31, ty = threadIdx.x >> 5;  // 32 x 8
#pragma unroll
    for (int i = 0; i < 32; i += 8)
        t[ty + i][tx] = f2bf(in[(size_t)(r0 + ty + i) * C + c0 + tx]);
    __syncthreads();
#pragma unroll
    for (int i = 0; i < 32; i += 8)
        out[(size_t)(c0 + ty + i) * R + r0 + tx] = t[tx][ty + i];
}

// -------- fused Wq/Wk/Wv transpose+convert into WqkvT[3072][2048] ------------
__global__ __launch_bounds__(256) void tr_wqkv(const float* __restrict__ Wq,
                                               const float* __restrict__ Wk,
                                               const float* __restrict__ Wv,
                                               unsigned short* __restrict__ WqkvT) {
    __shared__ unsigned short t[32][33];
    int bx = blockIdx.x;  // 0..95
    const float* src; int C, c0, orow;
    if (bx < 64)      { src = Wq; C = 2048; c0 = bx * 32;        orow = bx * 32; }
    else if (bx < 80) { src = Wk; C = 512;  c0 = (bx - 64) * 32; orow = 2048 + (bx - 64) * 32; }
    else              { src = Wv; C = 512;  c0 = (bx - 80) * 32; orow = 2560 + (bx - 80) * 32; }
    int r0 = blockIdx.y * 32;
    int tx = threadIdx.x & 31, ty = threadIdx.x >> 5;
#pragma unroll
    for (int i = 0; i < 32; i += 8)
        t[ty + i][tx] = f2bf(src[(size_t)(r0 + ty + i) * C + c0 + tx]);
    __syncthreads();
#pragma unroll
    for (int i = 0; i < 32; i += 8)
        WqkvT[(size_t)(orow + ty + i) * 2048 + r0 + tx] = t[tx][ty + i];
}

// -------- bf16 tiled transpose with input pitch, batched on z ----------------
__global__ __launch_bounds__(256) void tr_bf16(const unsigned short* __restrict__ in,
                                               unsigned short* __restrict__ out,
                                               int R, int C, int ipitch,
                                               size_t ibs, size_t obs) {
    __shared__ unsigned short t[32][33];
    in += (size_t)blockIdx.z * ibs; out += (size_t)blockIdx.z * obs;
    int c0 = blockIdx.x * 32, r0 = blockIdx.y * 32;
    int tx = threadIdx.x & 31, ty = threadIdx.x >> 5;
#pragma unroll
    for (int i = 0; i < 32; i += 8)
        t[ty + i][tx] = in[(size_t)(r0 + ty + i) * ipitch + c0 + tx];
    __syncthreads();
#pragma unroll
    for (int i = 0; i < 32; i += 8)
        out[(size_t)(c0 + ty + i) * R + r0 + tx] = t[tx][ty + i];
}

// ---------------- GEMM: C[M][N] = A[M][K] x Bt[N][K]^T + bias ----------------
// bias from 3 arrays split at columns s1/s2 (pass s1=s2=1<<30 for single bias).
template <bool OUT_F32>
__global__ __launch_bounds__(256) void gemm_bt(const unsigned short* __restrict__ A,
                                               const unsigned short* __restrict__ Bt,
                                               const float* __restrict__ b0,
                                               const float* __restrict__ b1,
                                               const float* __restrict__ b2,
                                               int s1, int s2,
                                               void* __restrict__ Cv,
                                               int M, int N, int K) {
    __shared__ unsigned short As[128 * 64];
    __shared__ unsigned short Bs[128 * 64];
    const int t = threadIdx.x;
    const int lane = t & 63;
    const int wave = t >> 6;
    const int qlane = lane & 15;
    const int quad = lane >> 4;
    const int wm = (wave >> 1) * 64;
    const int wn = (wave & 1) * 64;
    const int bm = blockIdx.y * 128;
    const int bn = blockIdx.x * 128;
    const int srow = t >> 3;
    const int scc = (t & 7) * 8;
    const int gc8 = (((t & 7) ^ (2 * ((t >> 5) & 3))) * 8);
    const int rsw = 2 * (qlane >> 2);

    floatx4 acc[4][4] = {};

    for (int k0 = 0; k0 < K; k0 += 64) {
        __syncthreads();
#pragma unroll
        for (int r = 0; r < 4; ++r) {
            int row = r * 32 + srow;
            gload_lds16(A + (size_t)(bm + row) * K + k0 + gc8, &As[row * 64 + scc]);
        }
#pragma unroll
        for (int r = 0; r < 4; ++r) {
            int row = r * 32 + srow;
            gload_lds16(Bt + (size_t)(bn + row) * K + k0 + gc8, &Bs[row * 64 + scc]);
        }
        __syncthreads();
#pragma unroll
        for (int kk = 0; kk < 2; ++kk) {
            short8 a[4], b[4];
#pragma unroll
            for (int i = 0; i < 4; ++i)
                a[i] = *(const short8*)&As[(wm + i * 16 + qlane) * 64 + ((kk * 4 + quad) ^ rsw) * 8];
#pragma unroll
            for (int j = 0; j < 4; ++j)
                b[j] = *(const short8*)&Bs[(wn + j * 16 + qlane) * 64 + ((kk * 4 + quad) ^ rsw) * 8];
#pragma unroll
            for (int i = 0; i < 4; ++i)
#pragma unroll
                for (int j = 0; j < 4; ++j)
                    acc[i][j] = MFMA(a[i], b[j], acc[i][j]);
        }
    }
#pragma unroll
    for (int j = 0; j < 4; ++j) {
        int col = bn + wn + j * 16 + qlane;
        int cc = col; const float* bp = b0;
        if (col >= s2)      { bp = b2; cc = col - s2; }
        else if (col >= s1) { bp = b1; cc = col - s1; }
        float bvv = bp[cc];
#pragma unroll
        for (int i = 0; i < 4; ++i) {
            int row0 = bm + wm + i * 16 + quad * 4;
#pragma unroll
            for (int r = 0; r < 4; ++r) {
                float v = acc[i][j][r] + bvv;
                if (OUT_F32)
                    ((float*)Cv)[(size_t)(row0 + r) * N + col] = v;
                else
                    ((unsigned short*)Cv)[(size_t)(row0 + r) * N + col] = f2bf(v);
            }
        }
    }
}

// ---------------- Flash attention (128-row Q tiles, 32 rows/wave) ------------
// grid (16 qtiles, 32 heads, 2 batch) = 1024 blocks, 256 threads.
// LDS = 40KB exactly (Ks dbuf 16K + Vts single 8K + Ps 16K) -> 4 blocks/CU,
// all 1024 blocks co-resident, zero dispatch tail. TWO barriers per kt:
//   stage V(kt) -> barrier#1 (V visible across waves — R8 lacked this and
//   raced: waves read Vts rows staged by other waves before they landed)
//   -> K(kt+1) prefetch (async across whole body) -> QK -> exp+Ps (Ps is
//   wave-private, lgkmcnt-ordered) -> PV+rowsum -> barrier#2 (drains K
//   prefetch after a full iteration of cover; protects Ks[nxt] + Vts reuse).
// Numerics: R4-proven path (fp32 fma scale inside exp2, half-up bf16 pack).
__global__ __launch_bounds__(256, 4) void attn_kernel(const unsigned short* __restrict__ qkv,
                                                      const unsigned short* __restrict__ vtb,
                                                      const float* __restrict__ mask,
                                                      unsigned short* __restrict__ ob) {
    const int qt = blockIdx.x;
    const int head = blockIdx.y;
    const int b = blockIdx.z;
    const int kvh = head >> 2;
    const int qcol = head * 64;
    const int kcol = 2048 + kvh * 64;   // K slice inside qkv row
    const int vch = kvh * 64;           // Vt channel base
    const int q0 = qt * 128;
    const int t = threadIdx.x;
    const int lane = t & 63;
    const int wave = t >> 6;
    const int qlane = lane & 15;
    const int quad = lane >> 4;
    const int wr = wave * 32;

    __shared__ unsigned short Ks[2][64 * 64];   // 16 KB (double buffer)
    __shared__ unsigned short Vts[64 * 64];     //  8 KB (single, staged per-kt)
    __shared__ unsigned short Ps[128 * 64];     // 16 KB (wave-private slabs)

    const int gc8 = (((t & 7) ^ (2 * ((t >> 5) & 3))) * 8);  // swizzled global chunk
    const int rsw = 2 * (qlane >> 2);                        // read-side swizzle
    const float scale2 = 0.125f * LOG2E;

    const unsigned short* vbase = vtb + (size_t)(b * 512 + vch) * S_;
    const float* mbase = mask + (size_t)b * S_;

    // Q fragments straight from global (16B contiguous per lane)
    short8 aq[2][2];
#pragma unroll
    for (int mi = 0; mi < 2; ++mi)
#pragma unroll
        for (int kk = 0; kk < 2; ++kk)
            aq[mi][kk] = *(const short8*)(qkv +
                (size_t)(b * S_ + q0 + wr + mi * 16 + qlane) * 3072 + qcol + kk * 32 + quad * 8);

    // stage K tile 0 into buf 0
    {
        int row = t >> 3;
#pragma unroll
        for (int i = 0; i < 2; ++i) {
            int rr = row + 32 * i;
            gload_lds16(qkv + (size_t)(b * S_ + rr) * 3072 + kcol + gc8,
                        &Ks[0][(rr * 8 + (t & 7)) * 8]);
        }
    }

    // ones B-fragment: B[k][0]=1 -> row-sum lands in column 0 of osum
    short8 ones;
    {
        short v = (qlane == 0) ? (short)0x3F80 : (short)0;
        ones = (short8){v, v, v, v, v, v, v, v};
    }

    floatx4 o[2][4] = {};
    floatx4 osum[2] = {};

    __syncthreads();

    for (int kt = 0; kt < 32; ++kt) {
        const int cur = kt & 1;

        // ---- (1) stage V(kt) into Vts (freed by previous barrier#2) ----
        {
            int row = t >> 3;
#pragma unroll
            for (int i = 0; i < 2; ++i) {
                int rr = row + 32 * i;
                gload_lds16(vbase + (size_t)rr * S_ + kt * 64 + gc8,
                            &Vts[(rr * 8 + (t & 7)) * 8]);
            }
        }
        // ---- (2) mask values for this kt ----
        float m2[4];
#pragma unroll
        for (int j = 0; j < 4; ++j)
            m2[j] = mbase[kt * 64 + j * 16 + qlane] * LOG2E;

        // ---- barrier #1: V(kt) visible to ALL waves before PV reads it ----
        __syncthreads();

        // ---- (3) K prefetch for kt+1 (async; drains only at barrier#2) ----
        if (kt < 31) {
            const int nxt = cur ^ 1;
            int kn = (kt + 1) * 64;
            int row = t >> 3;
#pragma unroll
            for (int i = 0; i < 2; ++i) {
                int rr = row + 32 * i;
                gload_lds16(qkv + (size_t)(b * S_ + kn + rr) * 3072 + kcol + gc8,
                            &Ks[nxt][(rr * 8 + (t & 7)) * 8]);
            }
        }

        // ---- (4) QK^T: 32 q-rows x 64 keys per wave (Ks[cur] resident) ----
        floatx4 s[2][4] = {};
#pragma unroll
        for (int j = 0; j < 4; ++j) {
            short8 bk0 = *(const short8*)&Ks[cur][(j * 16 + qlane) * 64 + ((0 + quad) ^ rsw) * 8];
            short8 bk1 = *(const short8*)&Ks[cur][(j * 16 + qlane) * 64 + ((4 + quad) ^ rsw) * 8];
#pragma unroll
            for (int mi = 0; mi < 2; ++mi) {
                s[mi][j] = MFMA(aq[mi][0], bk0, s[mi][j]);
                s[mi][j] = MFMA(aq[mi][1], bk1, s[mi][j]);
            }
        }

        // ---- (5) exp2 + P store (half-up round, hi16 store, swizzled) ----
#pragma unroll
        for (int mi = 0; mi < 2; ++mi)
#pragma unroll
            for (int j = 0; j < 4; ++j) {
                int ebase = (wr + mi * 16 + quad * 4) * 64 + 16 * (j ^ quad) + qlane;
#pragma unroll
                for (int r = 0; r < 4; ++r) {
                    float p = __builtin_amdgcn_exp2f(s[mi][j][r] * scale2 + m2[j]);
                    unsigned int u = __builtin_bit_cast(unsigned int, p) + 0x8000u;
                    Ps[ebase + r * 64] = (unsigned short)(u >> 16);
                }
            }

        // ---- (6) PV + row-sum: V from Vts; P a-frags from own wave's slab ----
#pragma unroll
        for (int kk = 0; kk < 2; ++kk) {
            short8 ap[2];
#pragma unroll
            for (int mi = 0; mi < 2; ++mi)
                ap[mi] = *(const short8*)&Ps[(wr + mi * 16 + qlane) * 64 + ((kk * 4 + quad) ^ rsw) * 8];
#pragma unroll
            for (int j2 = 0; j2 < 4; ++j2) {
                short8 bv = *(const short8*)&Vts[(j2 * 16 + qlane) * 64 + ((kk * 4 + quad) ^ rsw) * 8];
#pragma unroll
                for (int mi = 0; mi < 2; ++mi)
                    o[mi][j2] = MFMA(ap[mi], bv, o[mi][j2]);
            }
#pragma unroll
            for (int mi = 0; mi < 2; ++mi)
                osum[mi] = MFMA(ap[mi], ones, osum[mi]);
        }

        // ---- barrier #2: drains K(kt+1); protects Ks[nxt] + Vts rewrite ----
        __syncthreads();
    }

    // ---- epilogue: broadcast row-sum (col 0 of osum), normalize, store ----
#pragma unroll
    for (int mi = 0; mi < 2; ++mi)
#pragma unroll
        for (int r = 0; r < 4; ++r) {
            float sm = __shfl(osum[mi][r], quad * 16, 64);
            float inv = 1.0f / sm;
            int row = q0 + wr + mi * 16 + quad * 4 + r;
#pragma unroll
            for (int j2 = 0; j2 < 4; ++j2)
                ob[(size_t)(b * S_ + row) * H_ + qcol + j2 * 16 + qlane] = f2bf(o[mi][j2][r] * inv);
        }
}

extern "C" void kernel_launch(void* const* d_in, const int* in_sizes, int n_in,
                              void* d_out, int out_size, void* d_ws, size_t ws_size,
                              hipStream_t stream) {
    const float* x    = (const float*)d_in[0];
    const float* mask = (const float*)d_in[1];
    const float* Wq   = (const float*)d_in[2];
    const float* bq   = (const float*)d_in[3];
    const float* Wk   = (const float*)d_in[4];
    const float* bk   = (const float*)d_in[5];
    const float* Wv   = (const float*)d_in[6];
    const float* bv   = (const float*)d_in[7];
    const float* Wo   = (const float*)d_in[8];
    const float* bo   = (const float*)d_in[9];
    float* out = (float*)d_out;

    // workspace (bf16 elems), 56 MB total:
    //   x_bf [4096][2048] (later: attn out), qkv [4096][3072],
    //   vt [2][512][2048], WqkvT [3072][2048] (later: WoT [2048][2048])
    unsigned short* ws = (unsigned short*)d_ws;
    unsigned short* x_bf   = ws;
    unsigned short* qkv    = x_bf + (size_t)4096 * 2048;
    unsigned short* vt_buf = qkv + (size_t)4096 * 3072;
    unsigned short* WqkvT  = vt_buf + (size_t)2 * 512 * 2048;
    unsigned short* WoT    = WqkvT;           // aliased: Wo transposed after QKV GEMM
    unsigned short* a_buf  = x_bf;            // aliased: x consumed by QKV GEMM

    const int BIG = 1 << 30;
    dim3 blk(256);
    // x -> bf16
    conv_f2b<<<dim3(4096 * 2048 / 4 / 256), blk, 0, stream>>>(x, x_bf, 4096 * 2048 / 4);
    // Wq|Wk|Wv -> WqkvT [3072][2048] (one launch)
    tr_wqkv<<<dim3(96, 64), blk, 0, stream>>>(Wq, Wk, Wv, WqkvT);
    // fused QKV projection: [4096][2048] x [3072][2048]^T -> qkv [4096][3072]
    gemm_bt<false><<<dim3(24, 32), blk, 0, stream>>>(x_bf, WqkvT, bq, bk, bv, 2048, 2560,
                                                     qkv, 4096, 3072, 2048);
    // Wo -> WoT (into WqkvT's space, now dead)
    tr_f2b<<<dim3(64, 64), blk, 0, stream>>>(Wo, WoT, 2048, 2048);
    // per-batch V transpose: qkv[b][s][2560..3071] -> vt [b][512][S]
    tr_bf16<<<dim3(16, 64, 2), blk, 0, stream>>>(qkv + 2560, vt_buf, 2048, 512, 3072,
                                                 (size_t)2048 * 3072, (size_t)512 * 2048);
    // attention (writes a_buf = x_bf)
    attn_kernel<<<dim3(16, 32, 2), blk, 0, stream>>>(qkv, vt_buf, mask, a_buf);
    // output projection (f32 out)
    gemm_bt<true><<<dim3(16, 32), blk, 0, stream>>>(a_buf, WoT, bo, bo, bo, BIG, BIG,
                                                    out, 4096, 2048, 2048);
}